// Round 1
// 129.474 us; speedup vs baseline: 1.0450x; 1.0450x over previous
//
#include <hip/hip_runtime.h>

// Problem constants
#define H_  1024
#define W_  1024
#define B_  4
#define GH  16
#define GW  16
#define GD  8
#define NC  12
#define CELLF (GD * NC)      // 96 floats per (y,x) grid cell
#define YROWF (GW * CELLF)   // 1536 floats per grid y-row

// Tiling: block (64,4) = 256 threads; tile 64 wide x 16 tall; 4 rows/thread.
#define TW 64
#define TH 16
#define LROWS (TH + 2)       // 18 image rows in LDS (+1 halo each side)
#define LCOLS (TW + 2)       // 66 columns
#define RSTR  19             // padded row stride (floats) per (col,ch) column: 57 dwords/col, odd mod 32 -> conflict-free
#define CSTR  (3 * RSTR)     // 57 floats per column (3 channels)

typedef _Float16 h2 __attribute__((ext_vector_type(2)));
typedef float    f2 __attribute__((ext_vector_type(2)));

__device__ __forceinline__ h2 u2h(unsigned int u) { return __builtin_bit_cast(h2, u); }
// 8-byte LDS load at 4-byte alignment -> ds_read2_b32 (adjacent rows of transposed tile)
__device__ __forceinline__ f2 ldp(const float* p) { f2 r; __builtin_memcpy(&r, p, sizeof(r)); return r; }

__global__ __launch_bounds__(256, 6)
void fused_conv_slice(const float* __restrict__ grid,
                      const float* __restrict__ guide,
                      const float* __restrict__ image,
                      const float* __restrict__ conv_w,
                      const float* __restrict__ conv_b,
                      float* __restrict__ out)
{
    // Transposed image tile: s_imgT[col][ch][row], row-stride RSTR=19 floats.
    __shared__ float s_imgT[LCOLS * CSTR];     // 66*57*4 = 15048 B
    // f16 y-lerped tables, split for bank spread (same layout/numerics as before, TH rows now)
    __shared__ uint4 s_t128[TH][3 * GD];       // 6144 B
    __shared__ uint2 s_t64 [TH][3 * GD];       // 3072 B   (~24.3 KB total -> 6 blocks/CU)

    const int tx  = threadIdx.x;   // 0..63 (one wave per tyq)
    const int tyq = threadIdx.y;   // 0..3
    const int tid = tyq * 64 + tx;
    const int bx  = blockIdx.x;
    const int by  = blockIdx.y;
    const int b   = blockIdx.z;
    const int x0 = bx * TW;
    const int y0 = by * TH;
    const int imgbase = b * (H_ * W_ * 3);

    // ---- stage image tile (+1 halo) into transposed LDS ----
    #pragma unroll
    for (int it = 0; it < 5; ++it) {
        int p = tid + it * 256;
        if (p < LROWS * LCOLS) {
            int rr = p / LCOLS;
            int c  = p - rr * LCOLS;
            int yy = y0 - 1 + rr;
            int xx = x0 - 1 + c;
            float v0 = 0.f, v1 = 0.f, v2 = 0.f;
            if ((unsigned)yy < (unsigned)H_ && (unsigned)xx < (unsigned)W_) {
                const float* q = image + imgbase + (yy * W_ + xx) * 3;
                v0 = q[0]; v1 = q[1]; v2 = q[2];
            }
            float* d = s_imgT + c * CSTR + rr;
            d[0]        = v0;
            d[RSTR]     = v1;
            d[2 * RSTR] = v2;
        }
    }

    // ---- table fill: one (row, cell, z) corner per thread-iteration ----
    const float* gB = grid + b * (GH * GW * GD * NC);
    #pragma unroll
    for (int it = 0; it < 2; ++it) {
        int cidx = tid + it * 256;
        if (cidx < TH * 24) {                 // 16 rows * 3 cells * 8 z = 384 corners
            int rr  = cidx / 24;
            int rem = cidx - rr * 24;
            int s   = rem >> 3;               // cell slot 0..2
            int z   = rem & 7;
            float gyf = (y0 + rr + 0.5f) * (1.0f / 64.0f) - 0.5f;
            float fyf = floorf(gyf);
            float tyw = gyf - fyf;
            int iy  = (int)fyf;
            int yi0 = min(max(iy, 0), GH - 1);
            int yi1 = min(max(iy + 1, 0), GH - 1);
            float wy0 = 1.0f - tyw, wy1 = tyw;
            int cellx = min(max(bx - 1 + s, 0), GW - 1);
            const float4* G0 = (const float4*)(gB + yi0 * YROWF + cellx * CELLF + z * NC);
            const float4* G1 = (const float4*)(gB + yi1 * YROWF + cellx * CELLF + z * NC);
            float4 a0 = G0[0], a1 = G0[1], a2 = G0[2];
            float4 c0 = G1[0], c1 = G1[1], c2 = G1[2];
            h2 p0, p1, p2, p3, p4, p5;       // RTE casts: identical numerics to prior kernel
            p0.x = (_Float16)(wy0 * a0.x + wy1 * c0.x); p0.y = (_Float16)(wy0 * a0.y + wy1 * c0.y);
            p1.x = (_Float16)(wy0 * a0.z + wy1 * c0.z); p1.y = (_Float16)(wy0 * a0.w + wy1 * c0.w);
            p2.x = (_Float16)(wy0 * a1.x + wy1 * c1.x); p2.y = (_Float16)(wy0 * a1.y + wy1 * c1.y);
            p3.x = (_Float16)(wy0 * a1.z + wy1 * c1.z); p3.y = (_Float16)(wy0 * a1.w + wy1 * c1.w);
            p4.x = (_Float16)(wy0 * a2.x + wy1 * c2.x); p4.y = (_Float16)(wy0 * a2.y + wy1 * c2.y);
            p5.x = (_Float16)(wy0 * a2.z + wy1 * c2.z); p5.y = (_Float16)(wy0 * a2.w + wy1 * c2.w);
            int ci = s * GD + z;
            uint4 lo;
            lo.x = __builtin_bit_cast(unsigned int, p0);
            lo.y = __builtin_bit_cast(unsigned int, p1);
            lo.z = __builtin_bit_cast(unsigned int, p2);
            lo.w = __builtin_bit_cast(unsigned int, p3);
            uint2 hi;
            hi.x = __builtin_bit_cast(unsigned int, p4);
            hi.y = __builtin_bit_cast(unsigned int, p5);
            s_t128[rr][ci] = lo;
            s_t64 [rr][ci] = hi;
        }
    }

    // ---- guide prefetch (4 rows/thread) ----
    const int x  = x0 + tx;
    const int lr = tyq * 4;
    const int guidebase = b * (H_ * W_);
    float g4[4];
    #pragma unroll
    for (int j = 0; j < 4; ++j)
        g4[j] = guide[guidebase + (y0 + lr + j) * W_ + x];

    // ---- conv weights: uniform reads -> SGPRs ----
    float wgt[81];
    #pragma unroll
    for (int i = 0; i < 81; ++i) wgt[i] = conv_w[i];
    float bias0 = conv_b[0], bias1 = conv_b[1], bias2 = conv_b[2];

    __syncthreads();  // the ONLY barrier

    // ---- conv for this thread's 4 rows, packed 2-at-a-time (f32 pairs) ----
    // acc[g][o] = {out_row lr+2g, out_row lr+2g+1} for channel o
    f2 acc[2][3];
    #pragma unroll
    for (int o = 0; o < 3; ++o) {
        float bo = (o == 0) ? bias0 : (o == 1) ? bias1 : bias2;
        acc[0][o] = (f2){bo, bo};
        acc[1][o] = (f2){bo, bo};
    }

    const float* pb0 = s_imgT + tx * CSTR + lr;
    #pragma unroll
    for (int kw = 0; kw < 3; ++kw) {
        #pragma unroll
        for (int ci = 0; ci < 3; ++ci) {
            const float* pb = pb0 + kw * CSTR + ci * RSTR;
            // adjacent-row pairs q_i = {LDS row lr+i, lr+i+1}; single-base ds_read2_b32 w/ imm offsets
            f2 q0 = ldp(pb + 0);
            f2 q1 = ldp(pb + 1);
            f2 q2 = ldp(pb + 2);
            f2 q3 = ldp(pb + 3);
            f2 q4 = ldp(pb + 4);
            #pragma unroll
            for (int kh = 0; kh < 3; ++kh) {
                f2 vA = (kh == 0) ? q0 : (kh == 1) ? q1 : q2;   // rows (lr,lr+1)
                f2 vB = (kh == 0) ? q2 : (kh == 1) ? q3 : q4;   // rows (lr+2,lr+3)
                #pragma unroll
                for (int o = 0; o < 3; ++o) {
                    float w = wgt[((kh * 3 + kw) * 3 + ci) * 3 + o];
                    f2 ws = (f2){w, w};
                    acc[0][o] = __builtin_elementwise_fma(vA, ws, acc[0][o]);
                    acc[1][o] = __builtin_elementwise_fma(vB, ws, acc[1][o]);
                }
            }
        }
    }

    // ---- per-thread x-interp setup ----
    float gxf = (x + 0.5f) * (1.0f / 64.0f) - 0.5f;
    float fxf = floorf(gxf);
    float txw = gxf - fxf;
    float wxa = 1.0f - txw, wxb = txw;
    int s0 = (int)fxf - (bx - 1);   // table x-slot of left corner: 0 or 1

    const int outbase = b * (H_ * W_ * 3);

    #pragma unroll
    for (int j = 0; j < 4; ++j) {
        int R = lr + j;
        const uint4* T128 = &s_t128[R][0];
        const uint2* T64  = &s_t64 [R][0];

        float gzf = g4[j] * 8.0f - 0.5f;
        float fzf = floorf(gzf);
        float tz  = gzf - fzf;
        int iz = (int)fzf;                    // -1..7
        int zb = min(max(iz, 0), GD - 2);     // contiguous z-pair base
        float wA = (iz < 0) ? 1.0f : ((iz > GD - 2) ? 0.0f : (1.0f - tz));
        float wB = 1.0f - wA;

        float m0 = wxa * wA, m1 = wxa * wB, m2 = wxb * wA, m3 = wxb * wB;
        h2 m0h = {(_Float16)m0, (_Float16)m0};
        h2 m1h = {(_Float16)m1, (_Float16)m1};
        h2 m2h = {(_Float16)m2, (_Float16)m2};
        h2 m3h = {(_Float16)m3, (_Float16)m3};

        // corners: A=(s0,zb) B=(s0,zb+1) C=(s0+1,zb) D=(s0+1,zb+1)
        int ci0 = s0 * GD + zb;
        uint4 Alo = T128[ci0];          uint2 Ahi = T64[ci0];
        uint4 Blo = T128[ci0 + 1];      uint2 Bhi = T64[ci0 + 1];
        uint4 Clo = T128[ci0 + GD];     uint2 Chi = T64[ci0 + GD];
        uint4 Dlo = T128[ci0 + GD + 1]; uint2 Dhi = T64[ci0 + GD + 1];

        h2 A[6]  = {u2h(Alo.x), u2h(Alo.y), u2h(Alo.z), u2h(Alo.w), u2h(Ahi.x), u2h(Ahi.y)};
        h2 Bv[6] = {u2h(Blo.x), u2h(Blo.y), u2h(Blo.z), u2h(Blo.w), u2h(Bhi.x), u2h(Bhi.y)};
        h2 Cv[6] = {u2h(Clo.x), u2h(Clo.y), u2h(Clo.z), u2h(Clo.w), u2h(Chi.x), u2h(Chi.y)};
        h2 Dv[6] = {u2h(Dlo.x), u2h(Dlo.y), u2h(Dlo.z), u2h(Dlo.w), u2h(Dhi.x), u2h(Dhi.y)};

        // packed-f16 4-corner lerp
        h2 c[6];
        #pragma unroll
        for (int k = 0; k < 6; ++k)
            c[k] = __builtin_elementwise_fma(A[k], m0h,
                   __builtin_elementwise_fma(Bv[k], m1h,
                   __builtin_elementwise_fma(Cv[k], m2h, Dv[k] * m3h)));

        // apply: out_o = c[2o]·{a0,a1} + c[2o+1]·{a2,1}  (fdot2, f32 accumulate)
        float a0 = acc[j >> 1][0][j & 1];
        float a1 = acc[j >> 1][1][j & 1];
        float a2 = acc[j >> 1][2][j & 1];
        h2 q01 = {(_Float16)a0, (_Float16)a1};
        h2 q21 = {(_Float16)a2, (_Float16)1.0f};

        int oidx = outbase + ((y0 + R) * W_ + x) * 3;
        #pragma unroll
        for (int o3 = 0; o3 < 3; ++o3) {
            float t = __builtin_amdgcn_fdot2(c[2 * o3 + 1], q21, 0.0f, false);
            out[oidx + o3] = __builtin_amdgcn_fdot2(c[2 * o3], q01, t, false);
        }
    }
}

extern "C" void kernel_launch(void* const* d_in, const int* in_sizes, int n_in,
                              void* d_out, int out_size, void* d_ws, size_t ws_size,
                              hipStream_t stream) {
    const float* grid   = (const float*)d_in[0];
    const float* guide  = (const float*)d_in[1];
    const float* image  = (const float*)d_in[2];
    const float* conv_w = (const float*)d_in[3];
    const float* conv_b = (const float*)d_in[4];
    float* out = (float*)d_out;

    dim3 block(64, 4, 1);
    dim3 grid_dim(W_ / TW, H_ / TH, B_);  // (16, 64, 4)
    fused_conv_slice<<<grid_dim, block, 0, stream>>>(grid, guide, image, conv_w, conv_b, out);
}